// Round 1
// baseline (221.863 us; speedup 1.0000x reference)
//
#include <hip/hip_runtime.h>
#include <math.h>

// PMF implicit-feedback loss:
//   u = Uemb[user]; v = Vemb[item]                       [B,32] gathers
//   logits = rowdot(u,v)
//   bce = sum( max(x,0) + log1p(exp(-|x|)) - x*y )        stable logaddexp(0,x)
//   out = bce + 0.1*sqrt(sum u^2) + 0.1*sqrt(sum v^2)
//
// Layout: 8 lanes cooperate on one interaction; lane j loads float4 j of the
// 32-float row (coalesced 128B segment). Dot reduced with 3 shfl_xor steps.
// Per-thread partial sums -> wave butterfly -> LDS -> one atomicAdd per block.

#define BATCH_N   2000000
#define EMB_DIM   32

__global__ __launch_bounds__(256) void pmf_main(
    const int*   __restrict__ user,
    const int*   __restrict__ item,
    const float* __restrict__ ratings,
    const float* __restrict__ uemb,
    const float* __restrict__ vemb,
    float*       __restrict__ acc)   // acc[0]=bce, acc[1]=usq, acc[2]=vsq
{
    const int tid      = blockIdx.x * blockDim.x + threadIdx.x;
    const int nthreads = gridDim.x * blockDim.x;
    const int lane8    = threadIdx.x & 7;
    const long long ngroups = (long long)(nthreads >> 3);

    float bce = 0.0f, usq = 0.0f, vsq = 0.0f;

    for (long long g = (tid >> 3); g < BATCH_N; g += ngroups) {
        const int ui = user[g];
        const int vi = item[g];
        const float4 u4 = *(const float4*)(uemb + (long long)ui * EMB_DIM + lane8 * 4);
        const float4 v4 = *(const float4*)(vemb + (long long)vi * EMB_DIM + lane8 * 4);

        float d = u4.x*v4.x + u4.y*v4.y + u4.z*v4.z + u4.w*v4.w;
        usq += u4.x*u4.x + u4.y*u4.y + u4.z*u4.z + u4.w*u4.w;
        vsq += v4.x*v4.x + v4.y*v4.y + v4.z*v4.z + v4.w*v4.w;

        // reduce dot across the 8-lane group
        d += __shfl_xor(d, 1);
        d += __shfl_xor(d, 2);
        d += __shfl_xor(d, 4);

        if (lane8 == 0) {
            const float r = ratings[g];
            // logaddexp(0, d) - d*r, numerically stable
            bce += fmaxf(d, 0.0f) + log1pf(__expf(-fabsf(d))) - d * r;
        }
    }

    // 64-lane wave butterfly for each accumulator
    #pragma unroll
    for (int off = 1; off < 64; off <<= 1) {
        bce += __shfl_xor(bce, off);
        usq += __shfl_xor(usq, off);
        vsq += __shfl_xor(vsq, off);
    }

    __shared__ float sb[4], su[4], sv[4];
    const int wave = threadIdx.x >> 6;       // 4 waves per 256-thread block
    const int lane = threadIdx.x & 63;
    if (lane == 0) { sb[wave] = bce; su[wave] = usq; sv[wave] = vsq; }
    __syncthreads();
    if (threadIdx.x == 0) {
        float b = sb[0] + sb[1] + sb[2] + sb[3];
        float u = su[0] + su[1] + su[2] + su[3];
        float v = sv[0] + sv[1] + sv[2] + sv[3];
        atomicAdd(&acc[0], b);
        atomicAdd(&acc[1], u);
        atomicAdd(&acc[2], v);
    }
}

__global__ void pmf_final(const float* __restrict__ acc, float* __restrict__ out) {
    out[0] = acc[0] + 0.1f * (sqrtf(acc[1]) + sqrtf(acc[2]));
}

extern "C" void kernel_launch(void* const* d_in, const int* in_sizes, int n_in,
                              void* d_out, int out_size, void* d_ws, size_t ws_size,
                              hipStream_t stream) {
    const int*   user    = (const int*)  d_in[0];
    const int*   item    = (const int*)  d_in[1];
    const float* ratings = (const float*)d_in[2];
    const float* uemb    = (const float*)d_in[3];
    const float* vemb    = (const float*)d_in[4];
    float* acc = (float*)d_ws;
    float* out = (float*)d_out;

    // d_ws is poisoned with 0xAA before every timed call — zero the accumulators.
    hipMemsetAsync(acc, 0, 3 * sizeof(float), stream);

    // 2048 blocks x 256 threads = 8192 waves: full 32-waves/CU occupancy target,
    // 65536 groups of 8 lanes -> ~30 interactions per group (grid-stride).
    pmf_main<<<2048, 256, 0, stream>>>(user, item, ratings, uemb, vemb, acc);
    pmf_final<<<1, 1, 0, stream>>>(acc, out);
}

// Round 2
// 170.033 us; speedup vs baseline: 1.3048x; 1.3048x over previous
//
#include <hip/hip_runtime.h>
#include <math.h>

// PMF implicit-feedback loss:
//   u = Uemb[user]; v = Vemb[item]                       [B,32] gathers
//   logits = rowdot(u,v)
//   bce = sum( max(x,0) + log1p(exp(-|x|)) - x*y )        stable logaddexp(0,x)
//   out = bce + 0.1*sqrt(sum u^2) + 0.1*sqrt(sum v^2)
//
// Round 1 -> 2: latency-bound fix. 8 lanes/interaction (lane j loads float4 j
// of the 128B row, one cache line per gather). UNROLL=4: batch 8 index loads,
// then issue all 8 row gathers before computing -> 4x memory-level parallelism.
// Per-block partials in d_ws (no atomics, no memset); tiny reduce kernel.

#define BATCH_N   2000000
#define EMB_DIM   32
#define BLOCKS    2048
#define THREADS   256
#define NGROUPS   (BLOCKS * THREADS / 8)   // 65536 groups, ~30.5 interactions each

__global__ __launch_bounds__(THREADS) void pmf_main(
    const int*   __restrict__ user,
    const int*   __restrict__ item,
    const float* __restrict__ ratings,
    const float* __restrict__ uemb,
    const float* __restrict__ vemb,
    float*       __restrict__ partials)   // [3][BLOCKS]
{
    const int lane8 = threadIdx.x & 7;
    const long long gid    = (long long)blockIdx.x * (THREADS / 8) + (threadIdx.x >> 3);
    const long long stride = NGROUPS;

    float bce = 0.0f, usq = 0.0f, vsq = 0.0f;

    long long g = gid;
    // main loop, unrolled x4: all index loads, then all 8 gathers, then math
    for (; g + 3 * stride < BATCH_N; g += 4 * stride) {
        int   ui[4], vi[4];
        float r[4];
        #pragma unroll
        for (int k = 0; k < 4; ++k) {
            const long long gk = g + k * stride;
            ui[k] = __builtin_nontemporal_load(user + gk);
            vi[k] = __builtin_nontemporal_load(item + gk);
            r[k]  = __builtin_nontemporal_load(ratings + gk);
        }
        float4 u4[4], v4[4];
        #pragma unroll
        for (int k = 0; k < 4; ++k) {
            u4[k] = *(const float4*)(uemb + (long long)ui[k] * EMB_DIM + lane8 * 4);
            v4[k] = *(const float4*)(vemb + (long long)vi[k] * EMB_DIM + lane8 * 4);
        }
        #pragma unroll
        for (int k = 0; k < 4; ++k) {
            float d = u4[k].x*v4[k].x + u4[k].y*v4[k].y + u4[k].z*v4[k].z + u4[k].w*v4[k].w;
            usq += u4[k].x*u4[k].x + u4[k].y*u4[k].y + u4[k].z*u4[k].z + u4[k].w*u4[k].w;
            vsq += v4[k].x*v4[k].x + v4[k].y*v4[k].y + v4[k].z*v4[k].z + v4[k].w*v4[k].w;
            d += __shfl_xor(d, 1);
            d += __shfl_xor(d, 2);
            d += __shfl_xor(d, 4);
            if (lane8 == 0)
                bce += fmaxf(d, 0.0f) + log1pf(__expf(-fabsf(d))) - d * r[k];
        }
    }
    // tail
    for (; g < BATCH_N; g += stride) {
        const int ui = user[g];
        const int vi = item[g];
        const float4 u4 = *(const float4*)(uemb + (long long)ui * EMB_DIM + lane8 * 4);
        const float4 v4 = *(const float4*)(vemb + (long long)vi * EMB_DIM + lane8 * 4);
        float d = u4.x*v4.x + u4.y*v4.y + u4.z*v4.z + u4.w*v4.w;
        usq += u4.x*u4.x + u4.y*u4.y + u4.z*u4.z + u4.w*u4.w;
        vsq += v4.x*v4.x + v4.y*v4.y + v4.z*v4.z + v4.w*v4.w;
        d += __shfl_xor(d, 1);
        d += __shfl_xor(d, 2);
        d += __shfl_xor(d, 4);
        if (lane8 == 0) {
            const float r = ratings[g];
            bce += fmaxf(d, 0.0f) + log1pf(__expf(-fabsf(d))) - d * r;
        }
    }

    // 64-lane wave butterfly
    #pragma unroll
    for (int off = 1; off < 64; off <<= 1) {
        bce += __shfl_xor(bce, off);
        usq += __shfl_xor(usq, off);
        vsq += __shfl_xor(vsq, off);
    }

    __shared__ float sb[4], su[4], sv[4];
    const int wave = threadIdx.x >> 6;
    const int lane = threadIdx.x & 63;
    if (lane == 0) { sb[wave] = bce; su[wave] = usq; sv[wave] = vsq; }
    __syncthreads();
    if (threadIdx.x == 0) {
        partials[blockIdx.x]              = sb[0] + sb[1] + sb[2] + sb[3];
        partials[BLOCKS + blockIdx.x]     = su[0] + su[1] + su[2] + su[3];
        partials[2 * BLOCKS + blockIdx.x] = sv[0] + sv[1] + sv[2] + sv[3];
    }
}

__global__ __launch_bounds__(256) void pmf_final(
    const float* __restrict__ partials, float* __restrict__ out)
{
    float b = 0.0f, u = 0.0f, v = 0.0f;
    for (int i = threadIdx.x; i < BLOCKS; i += 256) {
        b += partials[i];
        u += partials[BLOCKS + i];
        v += partials[2 * BLOCKS + i];
    }
    #pragma unroll
    for (int off = 1; off < 64; off <<= 1) {
        b += __shfl_xor(b, off);
        u += __shfl_xor(u, off);
        v += __shfl_xor(v, off);
    }
    __shared__ float sb[4], su[4], sv[4];
    const int wave = threadIdx.x >> 6;
    const int lane = threadIdx.x & 63;
    if (lane == 0) { sb[wave] = b; su[wave] = u; sv[wave] = v; }
    __syncthreads();
    if (threadIdx.x == 0) {
        float bt = sb[0] + sb[1] + sb[2] + sb[3];
        float ut = su[0] + su[1] + su[2] + su[3];
        float vt = sv[0] + sv[1] + sv[2] + sv[3];
        out[0] = bt + 0.1f * (sqrtf(ut) + sqrtf(vt));
    }
}

extern "C" void kernel_launch(void* const* d_in, const int* in_sizes, int n_in,
                              void* d_out, int out_size, void* d_ws, size_t ws_size,
                              hipStream_t stream) {
    const int*   user    = (const int*)  d_in[0];
    const int*   item    = (const int*)  d_in[1];
    const float* ratings = (const float*)d_in[2];
    const float* uemb    = (const float*)d_in[3];
    const float* vemb    = (const float*)d_in[4];
    float* partials = (float*)d_ws;   // 3*BLOCKS floats, fully overwritten
    float* out      = (float*)d_out;

    pmf_main<<<BLOCKS, THREADS, 0, stream>>>(user, item, ratings, uemb, vemb, partials);
    pmf_final<<<1, 256, 0, stream>>>(partials, out);
}

// Round 3
// 161.936 us; speedup vs baseline: 1.3701x; 1.0500x over previous
//
#include <hip/hip_runtime.h>
#include <math.h>

// PMF implicit-feedback loss:
//   u = Uemb[user]; v = Vemb[item]                       [B,32] gathers
//   logits d = rowdot(u,v)
//   bce = sum( logaddexp(0,d) - d*r )
//   out = bce + 0.1*sqrt(sum u^2) + 0.1*sqrt(sum v^2)
//
// Round 2 -> 3: VALU-busy-time was constant ~62us across R1/R2 -> libm log1pf
// is the hog. Replace with 4th-order Taylor of logaddexp(0,x) (|x|<=~0.12 by
// input construction; exact __expf/__logf fallback for |x|>0.5, never taken).
// Unroll 4 -> 8 for 2x memory-level parallelism on the row gathers.

#define BATCH_N   2000000
#define EMB_DIM   32
#define BLOCKS    2048
#define THREADS   256
#define NGROUPS   (BLOCKS * THREADS / 8)   // 65536 groups of 8 lanes
#define UNROLL    8
#define LN2F      0.6931471805599453f

__device__ __forceinline__ float bce_term(float d, float r) {
    // logaddexp(0,d) - d*r; Taylor valid for |d| <= 0.5 (err < 6e-6/sample)
    if (__builtin_expect(fabsf(d) > 0.5f, 0)) {
        return fmaxf(d, 0.0f) + __logf(1.0f + __expf(-fabsf(d))) - d * r;
    }
    const float d2 = d * d;
    // ln2 + d*(0.5-r) + d^2/8 - d^4/192
    return fmaf(d, 0.5f - r, fmaf(d2, fmaf(d2, -1.0f / 192.0f, 0.125f), LN2F));
}

__global__ __launch_bounds__(THREADS) void pmf_main(
    const int*   __restrict__ user,
    const int*   __restrict__ item,
    const float* __restrict__ ratings,
    const float* __restrict__ uemb,
    const float* __restrict__ vemb,
    float*       __restrict__ partials)   // [3][BLOCKS]
{
    const int lane8 = threadIdx.x & 7;
    const float* ubase = uemb + lane8 * 4;   // lane's float4 slot within a row
    const float* vbase = vemb + lane8 * 4;
    const long long gid    = (long long)blockIdx.x * (THREADS / 8) + (threadIdx.x >> 3);
    const long long stride = NGROUPS;

    float bce = 0.0f, usq = 0.0f, vsq = 0.0f;

    long long g = gid;
    for (; g + (UNROLL - 1) * stride < BATCH_N; g += UNROLL * stride) {
        int   ui[UNROLL], vi[UNROLL];
        float r[UNROLL];
        #pragma unroll
        for (int k = 0; k < UNROLL; ++k) {
            const long long gk = g + k * stride;
            ui[k] = __builtin_nontemporal_load(user + gk);
            vi[k] = __builtin_nontemporal_load(item + gk);
            r[k]  = __builtin_nontemporal_load(ratings + gk);
        }
        float4 u4[UNROLL], v4[UNROLL];
        #pragma unroll
        for (int k = 0; k < UNROLL; ++k) {
            u4[k] = *(const float4*)(ubase + ((long long)(ui[k] << 5)));
            v4[k] = *(const float4*)(vbase + ((long long)(vi[k] << 5)));
        }
        #pragma unroll
        for (int k = 0; k < UNROLL; ++k) {
            float d = u4[k].x*v4[k].x + u4[k].y*v4[k].y + u4[k].z*v4[k].z + u4[k].w*v4[k].w;
            usq += u4[k].x*u4[k].x + u4[k].y*u4[k].y + u4[k].z*u4[k].z + u4[k].w*u4[k].w;
            vsq += v4[k].x*v4[k].x + v4[k].y*v4[k].y + v4[k].z*v4[k].z + v4[k].w*v4[k].w;
            d += __shfl_xor(d, 1);
            d += __shfl_xor(d, 2);
            d += __shfl_xor(d, 4);
            if (lane8 == 0) bce += bce_term(d, r[k]);
        }
    }
    // tail
    for (; g < BATCH_N; g += stride) {
        const int ui = user[g];
        const int vi = item[g];
        const float4 u4 = *(const float4*)(ubase + ((long long)(ui << 5)));
        const float4 v4 = *(const float4*)(vbase + ((long long)(vi << 5)));
        float d = u4.x*v4.x + u4.y*v4.y + u4.z*v4.z + u4.w*v4.w;
        usq += u4.x*u4.x + u4.y*u4.y + u4.z*u4.z + u4.w*u4.w;
        vsq += v4.x*v4.x + v4.y*v4.y + v4.z*v4.z + v4.w*v4.w;
        d += __shfl_xor(d, 1);
        d += __shfl_xor(d, 2);
        d += __shfl_xor(d, 4);
        if (lane8 == 0) bce += bce_term(d, ratings[g]);
    }

    // 64-lane wave butterfly
    #pragma unroll
    for (int off = 1; off < 64; off <<= 1) {
        bce += __shfl_xor(bce, off);
        usq += __shfl_xor(usq, off);
        vsq += __shfl_xor(vsq, off);
    }

    __shared__ float sb[4], su[4], sv[4];
    const int wave = threadIdx.x >> 6;
    const int lane = threadIdx.x & 63;
    if (lane == 0) { sb[wave] = bce; su[wave] = usq; sv[wave] = vsq; }
    __syncthreads();
    if (threadIdx.x == 0) {
        partials[blockIdx.x]              = sb[0] + sb[1] + sb[2] + sb[3];
        partials[BLOCKS + blockIdx.x]     = su[0] + su[1] + su[2] + su[3];
        partials[2 * BLOCKS + blockIdx.x] = sv[0] + sv[1] + sv[2] + sv[3];
    }
}

__global__ __launch_bounds__(256) void pmf_final(
    const float* __restrict__ partials, float* __restrict__ out)
{
    float b = 0.0f, u = 0.0f, v = 0.0f;
    for (int i = threadIdx.x; i < BLOCKS; i += 256) {
        b += partials[i];
        u += partials[BLOCKS + i];
        v += partials[2 * BLOCKS + i];
    }
    #pragma unroll
    for (int off = 1; off < 64; off <<= 1) {
        b += __shfl_xor(b, off);
        u += __shfl_xor(u, off);
        v += __shfl_xor(v, off);
    }
    __shared__ float sb[4], su[4], sv[4];
    const int wave = threadIdx.x >> 6;
    const int lane = threadIdx.x & 63;
    if (lane == 0) { sb[wave] = b; su[wave] = u; sv[wave] = v; }
    __syncthreads();
    if (threadIdx.x == 0) {
        float bt = sb[0] + sb[1] + sb[2] + sb[3];
        float ut = su[0] + su[1] + su[2] + su[3];
        float vt = sv[0] + sv[1] + sv[2] + sv[3];
        out[0] = bt + 0.1f * (sqrtf(ut) + sqrtf(vt));
    }
}

extern "C" void kernel_launch(void* const* d_in, const int* in_sizes, int n_in,
                              void* d_out, int out_size, void* d_ws, size_t ws_size,
                              hipStream_t stream) {
    const int*   user    = (const int*)  d_in[0];
    const int*   item    = (const int*)  d_in[1];
    const float* ratings = (const float*)d_in[2];
    const float* uemb    = (const float*)d_in[3];
    const float* vemb    = (const float*)d_in[4];
    float* partials = (float*)d_ws;   // 3*BLOCKS floats, fully overwritten
    float* out      = (float*)d_out;

    pmf_main<<<BLOCKS, THREADS, 0, stream>>>(user, item, ratings, uemb, vemb, partials);
    pmf_final<<<1, 256, 0, stream>>>(partials, out);
}